// Round 2
// baseline (452.608 us; speedup 1.0000x reference)
//
#include <hip/hip_runtime.h>
#include <math.h>

#define DEVI static __device__ __forceinline__

using bf16x8 = __attribute__((ext_vector_type(8))) __bf16;
using f32x4  = __attribute__((ext_vector_type(4))) float;

constexpr int Bb = 2, Tt = 2048, Dd = 2048, NQ = 16, NK = 4, HD = 128;
constexpr int Mrows = Bb * Tt;               // 4096
constexpr int QKC   = NQ*HD + NK*HD;         // 2560 (q,k fp32 cols)
constexpr int VC    = NK*HD;                 // 512
constexpr int KOFF  = NQ*HD;                 // 2048 (row offset of k-weights)
constexpr int VOFF  = NQ*HD + NK*HD;         // 2560 (row offset of v-weights)

DEVI ushort f2b(float f) {                   // fp32 -> bf16 (RNE)
  union { float f; unsigned u; } v; v.f = f;
  unsigned r = v.u + 0x7fffu + ((v.u >> 16) & 1u);
  return (ushort)(r >> 16);
}
DEVI float b2f(ushort u) {
  union { unsigned u; float f; } v; v.u = ((unsigned)u) << 16;
  return v.f;
}
DEVI void split2(float x, ushort& h, ushort& l) {
  ushort hb = f2b(x);
  h = hb;
  l = f2b(x - b2f(hb));
}

typedef const __attribute__((address_space(1))) unsigned* gp1;
typedef __attribute__((address_space(3))) unsigned* lp3;
DEVI void gload16(void* lds, const void* g) {
  __builtin_amdgcn_global_load_lds((gp1)g, (lp3)lds, 16, 0, 0);
}

// ---------------- fp32 -> split bf16 pair ----------------
__global__ void k_split_x(const float* __restrict__ x, ushort* __restrict__ oh,
                          ushort* __restrict__ ol, int n4) {
  int i = blockIdx.x * blockDim.x + threadIdx.x;
  if (i >= n4) return;
  float4 v = ((const float4*)x)[i];
  ushort4 h, l;
  split2(v.x, h.x, l.x); split2(v.y, h.y, l.y);
  split2(v.z, h.z, l.z); split2(v.w, h.w, l.w);
  ((ushort4*)oh)[i] = h;
  ((ushort4*)ol)[i] = l;
}

// ------- transpose + split: in fp32 [R][C] -> hi/lo bf16 [C][R] -------
__global__ void k_tconv_split(const float* __restrict__ in, ushort* __restrict__ outh,
                              ushort* __restrict__ outl, int R, int C) {
  __shared__ float t[32][33];
  const int c0 = blockIdx.x * 32, r0 = blockIdx.y * 32;
  const int tx = threadIdx.x, ty = threadIdx.y;
#pragma unroll
  for (int i = 0; i < 32; i += 8)
    t[ty + i][tx] = in[(size_t)(r0 + ty + i) * C + (c0 + tx)];
  __syncthreads();
#pragma unroll
  for (int i = 0; i < 32; i += 8) {
    ushort h, l;
    split2(t[tx][ty + i], h, l);
    size_t o = (size_t)(c0 + ty + i) * R + (r0 + tx);
    outh[o] = h;
    outl[o] = l;
  }
}

// ------- transpose + convert (single bf16) -------
__global__ void k_tconv(const float* __restrict__ in, ushort* __restrict__ out, int R, int C) {
  __shared__ float t[32][33];
  const int c0 = blockIdx.x * 32, r0 = blockIdx.y * 32;
  const int tx = threadIdx.x, ty = threadIdx.y;
#pragma unroll
  for (int i = 0; i < 32; i += 8)
    t[ty + i][tx] = in[(size_t)(r0 + ty + i) * C + (c0 + tx)];
  __syncthreads();
#pragma unroll
  for (int i = 0; i < 32; i += 8)
    out[(size_t)(c0 + ty + i) * R + (r0 + tx)] = f2b(t[tx][ty + i]);
}

// ---------------- split-precision QKV GEMM ----------------
// A = (Ah+Al) [M][Kd], Bt = (Bh+Bl) [N][Kd]; C = A*Bt^T via AhBh+AhBl+AlBh
// cols < QKC -> fp32 QKf; cols >= QKC -> bf16 Vb
__launch_bounds__(256)
__global__ void k_gemm_qkv(const ushort* __restrict__ Ah, const ushort* __restrict__ Al,
                           const ushort* __restrict__ Bh, const ushort* __restrict__ Bl,
                           float* __restrict__ Cqk, ushort* __restrict__ Cv) {
  __shared__ char Ash[8192], Asl[8192], Bsh[8192], Bsl[8192];
  const int Kd = Dd;
  const int tid = threadIdx.x;
  const int l = tid & 63, w = tid >> 6;
  const int wr = w >> 1, wc = w & 1;
  const int lr = l & 15, lk = l >> 4;
  const size_t row0 = (size_t)blockIdx.y * 128, col0 = (size_t)blockIdx.x * 128;

  f32x4 acc[4][4];
#pragma unroll
  for (int i = 0; i < 4; ++i)
#pragma unroll
    for (int j = 0; j < 4; ++j) acc[i][j] = (f32x4){0.f, 0.f, 0.f, 0.f};

  const int c0i = tid, c1i = tid + 256;
  const int ra0 = c0i >> 2, sa0 = (c0i & 3) ^ ((ra0 >> 1) & 3);
  const int ra1 = c1i >> 2, sa1 = (c1i & 3) ^ ((ra1 >> 1) & 3);

  for (int kt = 0; kt < Kd; kt += 32) {
    if (kt) __syncthreads();
    size_t a0 = (row0 + ra0) * Kd + kt + sa0 * 8, a1 = (row0 + ra1) * Kd + kt + sa1 * 8;
    size_t b0 = (col0 + ra0) * Kd + kt + sa0 * 8, b1 = (col0 + ra1) * Kd + kt + sa1 * 8;
    gload16(Ash + c0i * 16, Ah + a0);
    gload16(Ash + c1i * 16, Ah + a1);
    gload16(Asl + c0i * 16, Al + a0);
    gload16(Asl + c1i * 16, Al + a1);
    gload16(Bsh + c0i * 16, Bh + b0);
    gload16(Bsh + c1i * 16, Bh + b1);
    gload16(Bsl + c0i * 16, Bl + b0);
    gload16(Bsl + c1i * 16, Bl + b1);
    __syncthreads();
    bf16x8 fah[4], fal[4], fbh[4], fbl[4];
#pragma unroll
    for (int i = 0; i < 4; ++i) {
      int ra = wr * 64 + i * 16 + lr;
      int ao = ra * 64 + ((lk ^ ((ra >> 1) & 3)) << 4);
      fah[i] = *(const bf16x8*)(Ash + ao);
      fal[i] = *(const bf16x8*)(Asl + ao);
      int rb = wc * 64 + i * 16 + lr;
      int bo = rb * 64 + ((lk ^ ((rb >> 1) & 3)) << 4);
      fbh[i] = *(const bf16x8*)(Bsh + bo);
      fbl[i] = *(const bf16x8*)(Bsl + bo);
    }
#pragma unroll
    for (int i = 0; i < 4; ++i)
#pragma unroll
      for (int j = 0; j < 4; ++j) {
        acc[i][j] = __builtin_amdgcn_mfma_f32_16x16x32_bf16(fah[i], fbh[j], acc[i][j], 0, 0, 0);
        acc[i][j] = __builtin_amdgcn_mfma_f32_16x16x32_bf16(fah[i], fbl[j], acc[i][j], 0, 0, 0);
        acc[i][j] = __builtin_amdgcn_mfma_f32_16x16x32_bf16(fal[i], fbh[j], acc[i][j], 0, 0, 0);
      }
  }
  if (col0 < QKC) {
#pragma unroll
    for (int i = 0; i < 4; ++i) {
      size_t r = row0 + wr * 64 + i * 16 + lk * 4;
#pragma unroll
      for (int j = 0; j < 4; ++j) {
        size_t cc = col0 + wc * 64 + j * 16 + lr;
#pragma unroll
        for (int rg = 0; rg < 4; ++rg) Cqk[(r + rg) * QKC + cc] = acc[i][j][rg];
      }
    }
  } else {
#pragma unroll
    for (int i = 0; i < 4; ++i) {
      size_t r = row0 + wr * 64 + i * 16 + lk * 4;
#pragma unroll
      for (int j = 0; j < 4; ++j) {
        size_t cc = col0 + wc * 64 + j * 16 + lr - QKC;
#pragma unroll
        for (int rg = 0; rg < 4; ++rg) Cv[(r + rg) * VC + cc] = f2b(acc[i][j][rg]);
      }
    }
  }
}

// ---------------- plain bf16 GEMM (out-proj) ----------------
__launch_bounds__(256)
__global__ void k_gemm_bt(const ushort* __restrict__ A, const ushort* __restrict__ Bt,
                          float* __restrict__ C, int M, int N, int Kd) {
  __shared__ char As[8192];
  __shared__ char Bs[8192];
  const int tid = threadIdx.x;
  const int l = tid & 63, w = tid >> 6;
  const int wr = w >> 1, wc = w & 1;
  const int lr = l & 15, lk = l >> 4;
  const size_t row0 = (size_t)blockIdx.y * 128, col0 = (size_t)blockIdx.x * 128;

  f32x4 acc[4][4];
#pragma unroll
  for (int i = 0; i < 4; ++i)
#pragma unroll
    for (int j = 0; j < 4; ++j) acc[i][j] = (f32x4){0.f, 0.f, 0.f, 0.f};

  const int c0i = tid, c1i = tid + 256;
  const int ra0 = c0i >> 2, sa0 = (c0i & 3) ^ ((ra0 >> 1) & 3);
  const int ra1 = c1i >> 2, sa1 = (c1i & 3) ^ ((ra1 >> 1) & 3);

  for (int kt = 0; kt < Kd; kt += 32) {
    if (kt) __syncthreads();
    gload16(As + c0i * 16, A + (row0 + ra0) * Kd + kt + sa0 * 8);
    gload16(As + c1i * 16, A + (row0 + ra1) * Kd + kt + sa1 * 8);
    gload16(Bs + c0i * 16, Bt + (col0 + ra0) * Kd + kt + sa0 * 8);
    gload16(Bs + c1i * 16, Bt + (col0 + ra1) * Kd + kt + sa1 * 8);
    __syncthreads();
    bf16x8 af[4], bfr[4];
#pragma unroll
    for (int i = 0; i < 4; ++i) {
      int ra = wr * 64 + i * 16 + lr;
      af[i] = *(const bf16x8*)(As + ra * 64 + ((lk ^ ((ra >> 1) & 3)) << 4));
      int rb = wc * 64 + i * 16 + lr;
      bfr[i] = *(const bf16x8*)(Bs + rb * 64 + ((lk ^ ((rb >> 1) & 3)) << 4));
    }
#pragma unroll
    for (int i = 0; i < 4; ++i)
#pragma unroll
      for (int j = 0; j < 4; ++j)
        acc[i][j] = __builtin_amdgcn_mfma_f32_16x16x32_bf16(af[i], bfr[j], acc[i][j], 0, 0, 0);
  }
#pragma unroll
  for (int i = 0; i < 4; ++i) {
    size_t r = row0 + wr * 64 + i * 16 + lk * 4;
#pragma unroll
    for (int j = 0; j < 4; ++j) {
      size_t cc = col0 + wc * 64 + j * 16 + lr;
#pragma unroll
      for (int rg = 0; rg < 4; ++rg) C[(r + rg) * N + cc] = acc[i][j][rg];
    }
  }
}

// ---------------- RoPE table (double-precision trig) ----------------
__global__ void k_rope_tab(const int* __restrict__ pos, float* __restrict__ tab) {
  int idx = blockIdx.x * blockDim.x + threadIdx.x;
  if (idx >= Mrows * 64) return;
  int m = idx >> 6, i = idx & 63;
  double a = (double)pos[m] * exp2(-0.20762050593045952 * (double)i);
  tab[idx * 2]     = (float)cos(a);
  tab[idx * 2 + 1] = (float)sin(a);
}

// ------- RoPE: fp32 QKf -> rotated, split to hi/lo bf16 (Q and K) -------
__global__ void k_rope(const float* __restrict__ qkf, const float* __restrict__ tab,
                       ushort* __restrict__ Qh, ushort* __restrict__ Ql,
                       ushort* __restrict__ Kh, ushort* __restrict__ Kl) {
  int idx = blockIdx.x * blockDim.x + threadIdx.x;
  if (idx >= Mrows * 20 * 8) return;
  int chunk = idx & 7;
  int h20 = (idx >> 3) % 20;    // 16 q heads then 4 k heads
  int m = idx / 160;
  const float* p = qkf + (size_t)m * QKC + h20 * 128 + chunk * 8;
  float4 x1a = *(const float4*)p,        x1b = *(const float4*)(p + 4);
  float4 x2a = *(const float4*)(p + 64), x2b = *(const float4*)(p + 68);
  float x1[8] = {x1a.x, x1a.y, x1a.z, x1a.w, x1b.x, x1b.y, x1b.z, x1b.w};
  float x2[8] = {x2a.x, x2a.y, x2a.z, x2a.w, x2b.x, x2b.y, x2b.z, x2b.w};
  const float* tp = tab + ((size_t)m * 64 + chunk * 8) * 2;
  ushort4 h1[2], l1[2], h2[2], l2[2];
#pragma unroll
  for (int j = 0; j < 8; ++j) {
    float c = tp[2 * j], s = tp[2 * j + 1];
    float o1 = x1[j] * c - x2[j] * s;
    float o2 = x2[j] * c + x1[j] * s;
    ushort hh, ll;
    split2(o1, hh, ll);
    ((ushort*)h1)[j] = hh; ((ushort*)l1)[j] = ll;
    split2(o2, hh, ll);
    ((ushort*)h2)[j] = hh; ((ushort*)l2)[j] = ll;
  }
  size_t base;
  ushort *oh, *ol;
  if (h20 < 16) { base = (size_t)m * 2048 + h20 * 128 + chunk * 8; oh = Qh; ol = Ql; }
  else          { base = (size_t)m * 512 + (h20 - 16) * 128 + chunk * 8; oh = Kh; ol = Kl; }
  *(ushort4*)(oh + base)      = h1[0];
  *(ushort4*)(oh + base + 4)  = h1[1];
  *(ushort4*)(ol + base)      = l1[0];
  *(ushort4*)(ol + base + 4)  = l1[1];
  *(ushort4*)(oh + base + 64) = h2[0];
  *(ushort4*)(oh + base + 68) = h2[1];
  *(ushort4*)(ol + base + 64) = l2[0];
  *(ushort4*)(ol + base + 68) = l2[1];
}

// ------- V transpose: Vb [M][VC] -> VT[(b*4+g)*128 + h][s] -------
__global__ void k_vt(const ushort* __restrict__ vb, ushort* __restrict__ vt) {
  __shared__ ushort t[32][33];
  const int bg = blockIdx.z, bq = bg >> 2, g = bg & 3;
  const int s0 = blockIdx.x * 32, h0 = blockIdx.y * 32;
  const int tx = threadIdx.x, ty = threadIdx.y;
#pragma unroll
  for (int i = 0; i < 32; i += 8)
    t[ty + i][tx] = vb[(size_t)(bq * Tt + s0 + ty + i) * VC + g * HD + h0 + tx];
  __syncthreads();
#pragma unroll
  for (int i = 0; i < 32; i += 8)
    vt[((size_t)bg * HD + h0 + ty + i) * Tt + (s0 + tx)] = t[tx][ty + i];
}

// ---------------- causal GQA flash attention, split-precision QK^T ----------------
__launch_bounds__(256)
__global__ void k_flash(const ushort* __restrict__ Qhg, const ushort* __restrict__ Qlg,
                        const ushort* __restrict__ Khg, const ushort* __restrict__ Klg,
                        const ushort* __restrict__ vt, ushort* __restrict__ attn) {
  __shared__ char Ksh[64 * 256];   // K hi [s][h], XOR swizzle ((s&7)<<4)
  __shared__ char Ksl[64 * 256];   // K lo
  __shared__ char Vs[128 * 128];   // V^T [h][s], XOR swizzle ((h&7)<<4)
  __shared__ char Pl[4][2304];     // per-wave P: 16 rows x 144B pitch
  const int qt = (int)gridDim.x - 1 - (int)blockIdx.x;
  const int hid = blockIdx.y;
  const int bq = hid >> 4, n = hid & 15, g = n >> 2;
  const int tid = threadIdx.x, w = tid >> 6, l = tid & 63;
  const int lr = l & 15, lk = l >> 4;
  const int t0 = qt * 64;
  const int qrow = t0 + w * 16;

  bf16x8 qfh[4], qfl[4];
  {
    const size_t qb = ((size_t)(bq * Tt + qrow + lr)) * 2048 + n * HD + lk * 8;
#pragma unroll
    for (int kt = 0; kt < 4; ++kt) {
      qfh[kt] = *(const bf16x8*)(Qhg + qb + kt * 32);
      qfl[kt] = *(const bf16x8*)(Qlg + qb + kt * 32);
    }
  }
  f32x4 O[8];
#pragma unroll
  for (int hb = 0; hb < 8; ++hb) O[hb] = (f32x4){0.f, 0.f, 0.f, 0.f};
  float mrow[4] = {-INFINITY, -INFINITY, -INFINITY, -INFINITY};
  float lrow[4] = {0.f, 0.f, 0.f, 0.f};

  const size_t kgbase = (size_t)(bq * Tt) * VC + g * HD;
  const size_t vgbase = (size_t)(bq * 4 + g) * HD * Tt;

  for (int j = 0; j <= qt; ++j) {
    const int s0 = j * 64;
    if (j) __syncthreads();
#pragma unroll
    for (int cc = 0; cc < 4; ++cc) {
      int c = cc * 256 + tid;
      int srow = c >> 4;
      int oinK = ((c & 15) << 4) ^ ((srow & 7) << 4);
      size_t ksrc = kgbase + (size_t)(s0 + srow) * VC + (oinK >> 1);
      gload16(Ksh + c * 16, Khg + ksrc);
      gload16(Ksl + c * 16, Klg + ksrc);
      int hrow = c >> 3;
      int oinV = ((c & 7) << 4) ^ ((hrow & 7) << 4);
      gload16(Vs + c * 16, vt + vgbase + (size_t)hrow * Tt + s0 + (oinV >> 1));
    }
    __syncthreads();
    f32x4 sc[4];
#pragma unroll
    for (int ns = 0; ns < 4; ++ns) {
      f32x4 a = (f32x4){0.f, 0.f, 0.f, 0.f};
      int sl = ns * 16 + lr;
#pragma unroll
      for (int kt = 0; kt < 4; ++kt) {
        int inner = (kt * 64 + lk * 16) ^ ((sl & 7) << 4);
        bf16x8 kfh = *(const bf16x8*)(Ksh + sl * 256 + inner);
        bf16x8 kfl = *(const bf16x8*)(Ksl + sl * 256 + inner);
        a = __builtin_amdgcn_mfma_f32_16x16x32_bf16(qfh[kt], kfh, a, 0, 0, 0);
        a = __builtin_amdgcn_mfma_f32_16x16x32_bf16(qfl[kt], kfh, a, 0, 0, 0);
        a = __builtin_amdgcn_mfma_f32_16x16x32_bf16(qfh[kt], kfl, a, 0, 0, 0);
      }
      sc[ns] = a;
    }
    if (j == qt) {
#pragma unroll
      for (int ns = 0; ns < 4; ++ns) {
        int scol = s0 + ns * 16 + lr;
#pragma unroll
        for (int r = 0; r < 4; ++r)
          if (scol > t0 + w * 16 + lk * 4 + r) sc[ns][r] = -INFINITY;
      }
    }
    float scl[4], rs[4];
#pragma unroll
    for (int r = 0; r < 4; ++r) {
      float v0 = fmaxf(fmaxf(sc[0][r], sc[1][r]), fmaxf(sc[2][r], sc[3][r]));
#pragma unroll
      for (int d = 1; d < 16; d <<= 1) v0 = fmaxf(v0, __shfl_xor(v0, d));
      float mn = fmaxf(mrow[r], v0);
      scl[r] = __expf(mrow[r] - mn);
      mrow[r] = mn;
      rs[r] = 0.f;
    }
#pragma unroll
    for (int ns = 0; ns < 4; ++ns)
#pragma unroll
      for (int r = 0; r < 4; ++r) {
        float p = __expf(sc[ns][r] - mrow[r]);
        rs[r] += p;
        *(ushort*)(Pl[w] + (lk * 4 + r) * 144 + (ns * 16 + lr) * 2) = f2b(p);
      }
#pragma unroll
    for (int r = 0; r < 4; ++r) {
#pragma unroll
      for (int d = 1; d < 16; d <<= 1) rs[r] += __shfl_xor(rs[r], d);
      lrow[r] = lrow[r] * scl[r] + rs[r];
    }
#pragma unroll
    for (int hb = 0; hb < 8; ++hb)
#pragma unroll
      for (int r = 0; r < 4; ++r) O[hb][r] *= scl[r];
    bf16x8 pa[2];
#pragma unroll
    for (int kt2 = 0; kt2 < 2; ++kt2)
      pa[kt2] = *(const bf16x8*)(Pl[w] + lr * 144 + kt2 * 64 + lk * 16);
#pragma unroll
    for (int hb = 0; hb < 8; ++hb) {
      int h = hb * 16 + lr;
#pragma unroll
      for (int kt2 = 0; kt2 < 2; ++kt2) {
        int inner = (kt2 * 64 + lk * 16) ^ ((h & 7) << 4);
        bf16x8 vf = *(const bf16x8*)(Vs + h * 128 + inner);
        O[hb] = __builtin_amdgcn_mfma_f32_16x16x32_bf16(pa[kt2], vf, O[hb], 0, 0, 0);
      }
    }
  }
  float inv[4];
#pragma unroll
  for (int r = 0; r < 4; ++r) inv[r] = 1.f / lrow[r];
#pragma unroll
  for (int hb = 0; hb < 8; ++hb)
#pragma unroll
    for (int r = 0; r < 4; ++r) {
      size_t orow = (size_t)(bq * Tt + t0 + w * 16 + lk * 4 + r);
      attn[orow * 2048 + n * HD + hb * 16 + lr] = f2b(O[hb][r] * inv[r]);
    }
}

// ---------------- launch ----------------
extern "C" void kernel_launch(void* const* d_in, const int* in_sizes, int n_in,
                              void* d_out, int out_size, void* d_ws, size_t ws_size,
                              hipStream_t stream) {
  const float* X  = (const float*)d_in[0];
  const int*   qp = (const int*)d_in[1];
  const float* Wq = (const float*)d_in[2];
  const float* Wk = (const float*)d_in[3];
  const float* Wv = (const float*)d_in[4];
  const float* Wo = (const float*)d_in[5];
  float* out = (float*)d_out;
  char* ws = (char*)d_ws;

  ushort* Xh     = (ushort*)(ws + 0);            // 16.78 MB  (-> Qh after GEMM)
  ushort* Xl     = (ushort*)(ws + 16777216);     // 16.78 MB  (-> Ql)
  ushort* WqkvTh = (ushort*)(ws + 33554432);     // 12.58 MB  (-> Kh,Kl,VT)
  ushort* WqkvTl = (ushort*)(ws + 46137344);     // 12.58 MB
  ushort* WoT    = (ushort*)(ws + 58720256);     //  8.39 MB
  float*  QKf    = (float*) (ws + 67108864);     // 41.94 MB  (-> attn)
  ushort* Vb     = (ushort*)(ws + 109051904);    //  4.19 MB
  float*  tab    = (float*) (ws + 113246208);    //  2.10 MB  (end ~115.3 MB)

  ushort* Qh   = Xh;
  ushort* Ql   = Xl;
  ushort* Kh   = (ushort*)(ws + 33554432);
  ushort* Kl   = (ushort*)(ws + 37748736);
  ushort* VT   = (ushort*)(ws + 41943040);
  ushort* attn = (ushort*)(ws + 67108864);

  dim3 tb(32, 8);
  k_split_x<<<(Mrows * Dd / 4 + 255) / 256, 256, 0, stream>>>(X, Xh, Xl, Mrows * Dd / 4);
  k_tconv_split<<<dim3(64, 64), tb, 0, stream>>>(Wq, WqkvTh, WqkvTl, Dd, 2048);
  k_tconv_split<<<dim3(16, 64), tb, 0, stream>>>(Wk, WqkvTh + (size_t)KOFF * Dd,
                                                 WqkvTl + (size_t)KOFF * Dd, Dd, 512);
  k_tconv_split<<<dim3(16, 64), tb, 0, stream>>>(Wv, WqkvTh + (size_t)VOFF * Dd,
                                                 WqkvTl + (size_t)VOFF * Dd, Dd, 512);
  k_tconv<<<dim3(64, 64), tb, 0, stream>>>(Wo, WoT, 2048, 2048);
  k_gemm_qkv<<<dim3(24, 32), 256, 0, stream>>>(Xh, Xl, WqkvTh, WqkvTl, QKf, Vb);
  k_rope_tab<<<(Mrows * 64 + 255) / 256, 256, 0, stream>>>(qp, tab);
  k_rope<<<(Mrows * 160 + 255) / 256, 256, 0, stream>>>(QKf, tab, Qh, Ql, Kh, Kl);
  k_vt<<<dim3(Tt / 32, HD / 32, Bb * NK), tb, 0, stream>>>(Vb, VT);
  k_flash<<<dim3(Tt / 64, Bb * NQ), 256, 0, stream>>>(Qh, Ql, Kh, Kl, VT, attn);
  k_gemm_bt<<<dim3(Dd / 128, Mrows / 128), 256, 0, stream>>>(attn, WoT, out, Mrows, Dd, Dd);
}